// Round 8
// baseline (189.573 us; speedup 1.0000x reference)
//
#include <hip/hip_runtime.h>

// Lucas-Kanade sparse optical flow, 21x21 windows, Scharr gradients,
// Gaussian weights (sigma=2). B=16, H=W=1008, HS=WS=48, T=2304.
// Output: (B, T, 2, 2) float32 = [win_pos, vels].
//
// v4: identical structure to v3 (batched loads, single wait, register
// compute) but WITHOUT the __launch_bounds__ min-waves cap: v3's
// (256,4) forced <=128 VGPR onto a ~170-VGPR kernel -> ~40 regs/thread
// spilled to scratch ~= 250 MB extra traffic. Let the allocator breathe.

constexpr int HH   = 1008;
constexpr int WW   = 1008;
constexpr int WINN = 21;
constexpr int HSN  = 48;
constexpr int WSN  = 48;
constexpr int TN   = HSN * WSN;        // 2304
constexpr int SEGS = 4;
constexpr int WPB  = WSN / SEGS;       // 12 windows per block

// exp(-(y-10)^2 / 8)
__device__ __constant__ float kWY[WINN] = {
    3.7266532e-6f, 4.0065297e-5f, 3.3546262e-4f, 2.1874911e-3f,
    1.1108997e-2f, 4.3936934e-2f, 1.3533528e-1f, 3.2465247e-1f,
    6.0653066e-1f, 8.8249690e-1f, 1.0f,          8.8249690e-1f,
    6.0653066e-1f, 3.2465247e-1f, 1.3533528e-1f, 4.3936934e-2f,
    1.1108997e-2f, 2.1874911e-3f, 3.3546262e-4f, 4.0065297e-5f,
    3.7266532e-6f };

__global__ __launch_bounds__(256)
void SparseOptFlowLK_kernel(const float* __restrict__ imgs,
                            float* __restrict__ out) {
    const int bi  = blockIdx.x;                 // b*192 + hy*4 + seg
    const int b   = bi / (HSN * SEGS);
    const int rem = bi % (HSN * SEGS);
    const int hy  = rem / SEGS;
    const int seg = rem % SEGS;

    const float* __restrict__ ff = imgs + (size_t)b * (2ull * HH * WW);
    const float* __restrict__ sf = ff + (size_t)HH * WW;

    __shared__ float partial[4][5][256];        // [wave][sum][col] 20480 B
    __shared__ float red[WPB][5];

    const int  lx  = threadIdx.x;
    const int  wv  = lx >> 6;
    const int  ln  = lx & 63;
    const bool act = (ln < 63);
    const int  c0  = seg * 252 + 4 * ln;        // global col of lane's 4
    const int  r0  = 6 * wv;                    // first window-local row
    const int  nr  = (wv == 3) ? 3 : 6;         // rows this wave computes
    const int  g0  = hy * WINN;                 // first window row (global)

    // ---- batched loads: all independent, issued before any wait ----
    float4 ffv[8];                              // ff rows r0-1 .. r0+nr
    #pragma unroll
    for (int i = 0; i < 8; ++i) {
        ffv[i] = make_float4(0.f, 0.f, 0.f, 0.f);
        const int gr = g0 + r0 - 1 + i;
        if (act && i <= nr + 1 && gr >= 0 && gr < HH)
            ffv[i] = *reinterpret_cast<const float4*>(ff + (size_t)gr * WW + c0);
    }
    float4 sfv[6];                              // sf rows r0 .. r0+nr-1
    #pragma unroll
    for (int i = 0; i < 6; ++i) {
        sfv[i] = make_float4(0.f, 0.f, 0.f, 0.f);
        if (act && i < nr)
            sfv[i] = *reinterpret_cast<const float4*>(
                         sf + (size_t)(g0 + r0 + i) * WW + c0);
    }

    // horizontal halos: shuffle from neighbor lanes, edge lanes fix up
    // with (batched) scalar loads.
    float ffl[8], ffr[8];
    #pragma unroll
    for (int i = 0; i < 8; ++i) {
        ffl[i] = __shfl_up(ffv[i].w, 1);        // col c0-1
        ffr[i] = __shfl_down(ffv[i].x, 1);      // col c0+4
    }
    #pragma unroll
    for (int i = 0; i < 8; ++i) {
        const int  gr = g0 + r0 - 1 + i;
        const bool rv = (i <= nr + 1 && gr >= 0 && gr < HH);
        if (ln == 0)
            ffl[i] = (rv && c0 > 0)      ? ff[(size_t)gr * WW + c0 - 1] : 0.f;
        if (ln == 62)
            ffr[i] = (rv && c0 + 4 < WW) ? ff[(size_t)gr * WW + c0 + 4] : 0.f;
    }

    // per-lane x-weights (window-local x = col % 21; 252 = 12*21)
    float wx[4];
    {
        const int m = c0 % WINN;
        #pragma unroll
        for (int c = 0; c < 4; ++c) {
            int mc = m + c; if (mc >= WINN) mc -= WINN;
            const float dx = (float)(mc - 10);
            wx[c] = __expf(-dx * dx * 0.125f);
        }
    }

    // ---- register-resident compute ----
    float sA[4] = {0,0,0,0}, sB[4] = {0,0,0,0}, sD[4] = {0,0,0,0};
    float sX[4] = {0,0,0,0}, sY[4] = {0,0,0,0};

    #pragma unroll
    for (int yl = 0; yl < 6; ++yl) {
        if (yl < nr) {
            const float wy = kWY[r0 + yl];
            const float T[6]  = { ffl[yl],   ffv[yl].x,   ffv[yl].y,
                                  ffv[yl].z, ffv[yl].w,   ffr[yl] };
            const float M[6]  = { ffl[yl+1], ffv[yl+1].x, ffv[yl+1].y,
                                  ffv[yl+1].z, ffv[yl+1].w, ffr[yl+1] };
            const float Bo[6] = { ffl[yl+2], ffv[yl+2].x, ffv[yl+2].y,
                                  ffv[yl+2].z, ffv[yl+2].w, ffr[yl+2] };
            const float SF[4] = { sfv[yl].x, sfv[yl].y, sfv[yl].z, sfv[yl].w };

            #pragma unroll
            for (int c = 0; c < 4; ++c) {
                // Scharr (cross-correlation = XLA conv semantics)
                const float Ix = 3.0f * (T[c+2] - T[c]) + 10.0f * (M[c+2] - M[c])
                               + 3.0f * (Bo[c+2] - Bo[c]);
                const float Iy = 3.0f * (Bo[c] - T[c]) + 10.0f * (Bo[c+1] - T[c+1])
                               + 3.0f * (Bo[c+2] - T[c+2]);
                const float df = M[c+1] - SF[c];   // ff - sf
                const float w  = wx[c] * wy;
                const float wIx = w * Ix, wIy = w * Iy;
                sA[c] += wIx * Ix;
                sB[c] += wIx * Iy;
                sD[c] += wIy * Iy;
                sX[c] += wIx * df;
                sY[c] += wIy * df;
            }
        }
    }

    if (act) {
        *reinterpret_cast<float4*>(&partial[wv][0][4*ln]) = make_float4(sA[0],sA[1],sA[2],sA[3]);
        *reinterpret_cast<float4*>(&partial[wv][1][4*ln]) = make_float4(sB[0],sB[1],sB[2],sB[3]);
        *reinterpret_cast<float4*>(&partial[wv][2][4*ln]) = make_float4(sD[0],sD[1],sD[2],sD[3]);
        *reinterpret_cast<float4*>(&partial[wv][3][4*ln]) = make_float4(sX[0],sX[1],sX[2],sX[3]);
        *reinterpret_cast<float4*>(&partial[wv][4][4*ln]) = make_float4(sY[0],sY[1],sY[2],sY[3]);
    }
    __syncthreads();

    // reduce 4 waves x 21 cols -> per-window sums (12 windows x 5 = 60 thr)
    if (lx < WPB * 5) {
        const int k = lx / 5;
        const int s = lx % 5;
        float sum = 0.0f;
        #pragma unroll
        for (int w4 = 0; w4 < 4; ++w4) {
            #pragma unroll
            for (int j = 0; j < WINN; ++j)
                sum += partial[w4][s][k * WINN + j];
        }
        red[k][s] = sum;
    }
    __syncthreads();

    // solve 2x2 per window and store
    if (lx < WPB) {
        const float A  = red[lx][0];
        const float Bv = red[lx][1];
        const float D  = red[lx][2];
        const float Bx = red[lx][3];
        const float By = red[lx][4];

        const float det = A * D - Bv * Bv;
        const float inv = (det != 0.0f) ? (1.0f / det) : 0.0f;
        const float vx  = inv * ( D * Bx - Bv * By);
        const float vy  = inv * (-Bv * Bx + A  * By);

        const int wxg = seg * WPB + lx;         // global window col 0..47
        const float wpx = 2.0f * (float)(wxg * WINN + WINN / 2) / (float)WW - 1.0f;
        const float wpy = 2.0f * (float)(hy  * WINN + WINN / 2) / (float)HH - 1.0f;

        float4 o;
        o.x = wpx;
        o.y = wpy;
        o.z = vx / 48.0f + wpx;                 // CENTER_REL = [48,48]
        o.w = vy / 48.0f + wpy;
        reinterpret_cast<float4*>(out)[(size_t)b * TN + hy * WSN + wxg] = o;
    }
}

extern "C" void kernel_launch(void* const* d_in, const int* in_sizes, int n_in,
                              void* d_out, int out_size, void* d_ws, size_t ws_size,
                              hipStream_t stream) {
    const float* imgs = (const float*)d_in[0];
    float* out = (float*)d_out;

    const int B = in_sizes[0] / (2 * HH * WW);  // 16
    const dim3 grid(B * HSN * SEGS);            // 3072 blocks
    SparseOptFlowLK_kernel<<<grid, 256, 0, stream>>>(imgs, out);
}

// Round 9
// 182.976 us; speedup vs baseline: 1.0361x; 1.0361x over previous
//
#include <hip/hip_runtime.h>

// Lucas-Kanade sparse optical flow, 21x21 windows, Scharr gradients,
// Gaussian weights (sigma=2). B=16, H=W=1008, HS=WS=48, T=2304.
// Output: (B, T, 2, 2) float32 = [win_pos, vels].
//
// v5 = v1 (champion: lean scalar rolling window, 3072 blocks, high
// occupancy) minus its register fat:
//  - y-weights are compile-time literals (constexpr + full unroll),
//    not a 21-entry runtime expf table (saves ~21 live VGPR + ~400
//    VALU instrs of libm guard code per thread)
//  - single __expf for the per-thread x-weight
// Target: VGPR <= 48 -> 8 waves/SIMD, 2x the wave-level latency hiding.

constexpr int HH   = 1008;
constexpr int WW   = 1008;
constexpr int WINN = 21;
constexpr int HSN  = 48;
constexpr int WSN  = 48;
constexpr int TN   = HSN * WSN;        // 2304
constexpr int SEGS = 4;
constexpr int COLS = WW / SEGS;        // 252 active columns per block
constexpr int WPB  = WSN / SEGS;       // 12 windows per block

// exp(-(y-10)^2/8) — constexpr: unrolled loop folds these to literals.
constexpr float kWY[WINN] = {
    3.7266532e-6f, 4.0065297e-5f, 3.3546262e-4f, 2.1874911e-3f,
    1.1108997e-2f, 4.3936934e-2f, 1.3533528e-1f, 3.2465247e-1f,
    6.0653066e-1f, 8.8249690e-1f, 1.0f,          8.8249690e-1f,
    6.0653066e-1f, 3.2465247e-1f, 1.3533528e-1f, 4.3936934e-2f,
    1.1108997e-2f, 2.1874911e-3f, 3.3546262e-4f, 4.0065297e-5f,
    3.7266532e-6f };

__global__ __launch_bounds__(256)
void SparseOptFlowLK_kernel(const float* __restrict__ imgs,
                            float* __restrict__ out) {
    const int bi  = blockIdx.x;                 // b*192 + hy*4 + seg
    const int b   = bi / (HSN * SEGS);
    const int rem = bi % (HSN * SEGS);
    const int hy  = rem / SEGS;                 // window-row 0..47
    const int seg = rem % SEGS;                 // quarter 0..3

    const float* __restrict__ ff = imgs + (size_t)b * (2ull * HH * WW);
    const float* __restrict__ sf = ff + (size_t)HH * WW;

    __shared__ float colsum[5][COLS];           // per-column partial sums
    __shared__ float red[WPB][5];               // per-window sums

    const int lx = threadIdx.x;

    if (lx < COLS) {
        const int gx = seg * COLS + lx;         // global column
        const bool hl = (gx > 0);
        const bool hr = (gx < WW - 1);

        // x-weight: exp(-((x-10)^2)/8), x = window-local col = lx % 21
        // (252 = 12*21, so segment-local == window-local)
        const float dxw = (float)(lx % WINN - 10);
        const float wxw = __expf(-dxw * dxw * 0.125f);

        const int g0 = hy * WINN;               // first window row (global)

        // rolling 3-row x 3-col register window
        float rm0, rm1, rm2, rc0, rc1, rc2;
        if (g0 > 0) {
            const float* r = ff + (size_t)(g0 - 1) * WW;
            rm1 = r[gx];
            rm0 = hl ? r[gx - 1] : 0.0f;
            rm2 = hr ? r[gx + 1] : 0.0f;
        } else {
            rm0 = rm1 = rm2 = 0.0f;             // SAME zero pad (top edge)
        }
        {
            const float* r = ff + (size_t)g0 * WW;
            rc1 = r[gx];
            rc0 = hl ? r[gx - 1] : 0.0f;
            rc2 = hr ? r[gx + 1] : 0.0f;
        }

        float sA = 0.0f, sB = 0.0f, sD = 0.0f, sX = 0.0f, sY = 0.0f;

        #pragma unroll
        for (int y = 0; y < WINN; ++y) {
            float rp0, rp1, rp2;
            const int gp = g0 + y + 1;
            if (gp < HH) {
                const float* r = ff + (size_t)gp * WW;
                rp1 = r[gx];
                rp0 = hl ? r[gx - 1] : 0.0f;
                rp2 = hr ? r[gx + 1] : 0.0f;
            } else {
                rp0 = rp1 = rp2 = 0.0f;         // SAME zero pad (bottom edge)
            }

            // Scharr (cross-correlation = XLA conv semantics)
            const float Ix = 3.0f * (rm2 - rm0) + 10.0f * (rc2 - rc0) + 3.0f * (rp2 - rp0);
            const float Iy = 3.0f * (rp0 - rm0) + 10.0f * (rp1 - rm1) + 3.0f * (rp2 - rm2);

            const float df = rc1 - sf[(size_t)(g0 + y) * WW + gx];   // ff - sf
            const float w  = wxw * kWY[y];      // kWY[y] is a literal

            const float wIx = w * Ix, wIy = w * Iy;
            sA += wIx * Ix;
            sB += wIx * Iy;
            sD += wIy * Iy;
            sX += wIx * df;
            sY += wIy * df;

            rm0 = rc0; rm1 = rc1; rm2 = rc2;
            rc0 = rp0; rc1 = rp1; rc2 = rp2;
        }

        colsum[0][lx] = sA;
        colsum[1][lx] = sB;
        colsum[2][lx] = sD;
        colsum[3][lx] = sX;
        colsum[4][lx] = sY;
    }
    __syncthreads();

    // reduce 21 columns -> per-window sums (12 windows x 5 sums = 60 thr)
    if (lx < WPB * 5) {
        const int w = lx / 5;
        const int s = lx % 5;
        float sum = 0.0f;
        #pragma unroll
        for (int j = 0; j < WINN; ++j) sum += colsum[s][w * WINN + j];
        red[w][s] = sum;
    }
    __syncthreads();

    // solve 2x2 per window and store
    if (lx < WPB) {
        const float A  = red[lx][0];
        const float Bv = red[lx][1];
        const float D  = red[lx][2];
        const float Bx = red[lx][3];
        const float By = red[lx][4];

        const float det = A * D - Bv * Bv;
        const float inv = (det != 0.0f) ? (1.0f / det) : 0.0f;
        const float vx  = inv * ( D * Bx - Bv * By);
        const float vy  = inv * (-Bv * Bx + A  * By);

        const int wxg = seg * WPB + lx;         // global window col 0..47
        const float wpx = 2.0f * (float)(wxg * WINN + WINN / 2) / (float)WW - 1.0f;
        const float wpy = 2.0f * (float)(hy  * WINN + WINN / 2) / (float)HH - 1.0f;

        float4 o;
        o.x = wpx;
        o.y = wpy;
        o.z = vx / 48.0f + wpx;                 // CENTER_REL = [48,48]
        o.w = vy / 48.0f + wpy;
        reinterpret_cast<float4*>(out)[(size_t)b * TN + hy * WSN + wxg] = o;
    }
}

extern "C" void kernel_launch(void* const* d_in, const int* in_sizes, int n_in,
                              void* d_out, int out_size, void* d_ws, size_t ws_size,
                              hipStream_t stream) {
    const float* imgs = (const float*)d_in[0];
    float* out = (float*)d_out;

    const int B = in_sizes[0] / (2 * HH * WW);  // 16
    const dim3 grid(B * HSN * SEGS);            // 3072 blocks
    SparseOptFlowLK_kernel<<<grid, 256, 0, stream>>>(imgs, out);
}